// Round 2
// baseline (565.842 us; speedup 1.0000x reference)
//
#include <hip/hip_runtime.h>
#include <stdint.h>

#define M_CH       384
#define TR         15
#define MARGIN     20
#define CHUNK_ROWS 16
#define BM_WORDS   192        // words per chunk = 16*384/32
#define WPR        12         // words per row = 384/32
#define WIN_ROWS   46         // CHUNK_ROWS + 2*TR

// decoupled-lookback status word: value in low 30 bits
#define VMASK  0x3FFFFFFFu
#define AGG_F  (1u << 30)
#define INCL_F (1u << 31)

// spread 8 bits of x to positions 0,4,8,...,28
__device__ __forceinline__ uint32_t spread4(uint32_t x) {
    x = (x | (x << 12)) & 0x000F000Fu;
    x = (x | (x << 6))  & 0x03030303u;
    x = (x | (x << 3))  & 0x11111111u;
    return x;
}

// ---------------- K1: streaming threshold pass ----------------
// Roles by blockIdx: [0, nbrBlock) threshold; == nbrBlock neighbor masks;
// > nbrBlock: pre-fill output with -1 and zero the scan-status array.
// Wave handles 256 contiguous float4s (1024 samples = 32 words).
__global__ __launch_bounds__(256)
void cand_kernel(const float* __restrict__ traces,
                 const float* __restrict__ locs,
                 long n4, long nwords, int nbrBlock,
                 uint32_t* __restrict__ candWords,
                 uint32_t* __restrict__ nEntries,
                 uint8_t* __restrict__ entryWord,
                 uint32_t* __restrict__ entryMask,
                 uint32_t* __restrict__ status, int nStat,
                 int maxdet, int* __restrict__ times, int* __restrict__ chans) {
    if ((int)blockIdx.x > nbrBlock) {
        // ---- fill role: poison-proof init (emit overwrites [0,total)) ----
        int i = ((int)blockIdx.x - nbrBlock - 1) * 256 + threadIdx.x;
        if (i < maxdet) { times[i] = -1; chans[i] = -1; }
        if (i < nStat)  status[i] = 0u;
        return;
    }
    if ((int)blockIdx.x == nbrBlock) {
        // ---- neighbor-mask role (one block) ----
        __shared__ float lx[M_CH], ly[M_CH];
        const int t = threadIdx.x;
        for (int c = t; c < M_CH; c += 256) {
            lx[c] = locs[2 * c];
            ly[c] = locs[2 * c + 1];
        }
        __syncthreads();
        for (int c0 = t; c0 < M_CH; c0 += 256) {
            float x = lx[c0], y = ly[c0];
            int ne = 0;
            for (int k = 0; k < WPR; ++k) {
                uint32_t mk = 0;
                #pragma unroll
                for (int b = 0; b < 32; ++b) {
                    int c = k * 32 + b;
                    float dx = x - lx[c], dy = y - ly[c];
                    if (sqrtf(dx * dx + dy * dy) <= 100.0f) mk |= 1u << b;
                }
                if (mk) {
                    entryWord[c0 * WPR + ne] = (uint8_t)k;
                    entryMask[c0 * WPR + ne] = mk;
                    ne++;
                }
            }
            nEntries[c0] = (uint32_t)ne;
        }
        return;
    }

    const int lane = threadIdx.x & 63;
    const long wv = (((long)blockIdx.x * 256) + threadIdx.x) >> 6;
    const long fb = wv * 256;                  // first float4 of this wave
    uint64_t B00,B01,B02,B03, B10,B11,B12,B13,
             B20,B21,B22,B23, B30,B31,B32,B33;
    {
        float4 v0 = make_float4(0,0,0,0), v1 = v0, v2 = v0, v3 = v0;
        long i0 = fb + 0 * 64 + lane;
        long i1 = fb + 1 * 64 + lane;
        long i2 = fb + 2 * 64 + lane;
        long i3 = fb + 3 * 64 + lane;
        if (i0 < n4) v0 = ((const float4*)traces)[i0];
        if (i1 < n4) v1 = ((const float4*)traces)[i1];
        if (i2 < n4) v2 = ((const float4*)traces)[i2];
        if (i3 < n4) v3 = ((const float4*)traces)[i3];
        B00 = __ballot(v0.x <= -3.0f); B01 = __ballot(v0.y <= -3.0f);
        B02 = __ballot(v0.z <= -3.0f); B03 = __ballot(v0.w <= -3.0f);
        B10 = __ballot(v1.x <= -3.0f); B11 = __ballot(v1.y <= -3.0f);
        B12 = __ballot(v1.z <= -3.0f); B13 = __ballot(v1.w <= -3.0f);
        B20 = __ballot(v2.x <= -3.0f); B21 = __ballot(v2.y <= -3.0f);
        B22 = __ballot(v2.z <= -3.0f); B23 = __ballot(v2.w <= -3.0f);
        B30 = __ballot(v3.x <= -3.0f); B31 = __ballot(v3.y <= -3.0f);
        B32 = __ballot(v3.z <= -3.0f); B33 = __ballot(v3.w <= -3.0f);
    }
    if (lane < 32) {
        int k  = lane >> 3;           // which load group
        int sh = (lane & 7) * 8;      // which byte of the ballot
        uint64_t b0 = (k & 2) ? ((k & 1) ? B30 : B20) : ((k & 1) ? B10 : B00);
        uint64_t b1 = (k & 2) ? ((k & 1) ? B31 : B21) : ((k & 1) ? B11 : B01);
        uint64_t b2 = (k & 2) ? ((k & 1) ? B32 : B22) : ((k & 1) ? B12 : B02);
        uint64_t b3 = (k & 2) ? ((k & 1) ? B33 : B23) : ((k & 1) ? B13 : B03);
        uint32_t w = spread4((uint32_t)(b0 >> sh) & 0xFFu)
                   | (spread4((uint32_t)(b1 >> sh) & 0xFFu) << 1)
                   | (spread4((uint32_t)(b2 >> sh) & 0xFFu) << 2)
                   | (spread4((uint32_t)(b3 >> sh) & 0xFFu) << 3);
        long wIdx = wv * 32 + lane;
        if (wIdx < nwords) candWords[wIdx] = w;
    }
}

// ---------------- K2: fused validate + decoupled-lookback scan + emit ----
// Block = 192 threads = one 16-row chunk. Valid bits never leave the block:
// validate from the LDS-staged window, count, get the global exclusive
// prefix via wave-parallel decoupled lookback (waits on EARLIER blocks
// only; device-scope atomics carry the value inside the status word), then
// emit in row-major order via an in-block ordered prefix.
__global__ __launch_bounds__(192)
void fused_kernel(const float* __restrict__ traces, int N, long nwords,
                  const uint32_t* __restrict__ nEntries,
                  const uint8_t* __restrict__ entryWord,
                  const uint32_t* __restrict__ entryMask,
                  const uint32_t* __restrict__ candWords,
                  uint32_t* __restrict__ status,
                  int maxdet, int* __restrict__ times, int* __restrict__ chans) {
    __shared__ uint32_t win[WIN_ROWS * WPR];   // 552 words = 2.2 KB
    __shared__ uint32_t wtot[3];
    __shared__ uint32_t exclSh;
    const int t = threadIdx.x;
    const int bid = (int)blockIdx.x;
    const int r0 = bid * CHUNK_ROWS;

    {
        const long gbase = (long)(r0 - TR) * WPR;
        #pragma unroll
        for (int i0 = 0; i0 < WIN_ROWS * WPR; i0 += 192) {
            int i = i0 + t;
            if (i < WIN_ROWS * WPR) {
                long g = gbase + i;
                win[i] = (g >= 0 && g < nwords) ? candWords[g] : 0u;
            }
        }
    }
    __syncthreads();

    const int lr = t / WPR;        // local row 0..15
    const int wi = t - lr * WPR;   // word-in-row 0..11
    const int r  = r0 + lr;
    const long w = (long)bid * BM_WORDS + t;

    uint32_t out = 0;
    if (w < nwords) {
        uint32_t word = win[(lr + TR) * WPR + wi];
        if (word && r >= MARGIN && r < N - MARGIN) {
            out = word;
            uint32_t tmp = word;
            while (tmp) {
                int bit = __ffs(tmp) - 1;
                tmp &= tmp - 1;
                const int c = wi * 32 + bit;
                const uint32_t selfbit = 1u << bit;
                const int ne = (int)nEntries[c];

                // ---- fast pass: any competitor bit anywhere in window? ----
                uint32_t anyComp = 0;
                for (int k = 0; k < ne; ++k) {
                    int wiE = (int)entryWord[c * WPR + k];
                    uint32_t em = entryMask[c * WPR + k];
                    const uint32_t* colp = &win[lr * WPR + wiE];
                    uint32_t orw = 0;
                    #pragma unroll
                    for (int dt = 0; dt < 31; ++dt) {
                        uint32_t h = colp[dt * WPR];
                        if (dt == TR) h &= (wiE == wi) ? ~selfbit : 0xFFFFFFFFu;
                        orw |= h & em;
                    }
                    anyComp |= orw;
                }

                if (anyComp) {
                    // ---- slow path: value comparison on actual hits ----
                    float raw = traces[(long)r * M_CH + c];
                    bool bad = false;
                    for (int k = 0; k < ne && !bad; ++k) {
                        int wiE = (int)entryWord[c * WPR + k];
                        uint32_t em = entryMask[c * WPR + k];
                        const uint32_t* colp = &win[lr * WPR + wiE];
                        #pragma unroll
                        for (int dt = 0; dt < 31; ++dt) {
                            uint32_t h = colp[dt * WPR] & em;
                            if (dt == TR && wiE == wi) h &= ~selfbit;
                            while (h) {
                                int b2 = __ffs(h) - 1;
                                h &= h - 1;
                                float v = traces[(long)(r - TR + dt) * M_CH + wiE * 32 + b2];
                                if (v < raw) bad = true;
                            }
                        }
                    }
                    if (bad) out &= ~selfbit;
                }
            }
        }
    }

    // ---- in-block ordered prefix of popcounts (words ascending = rows) ----
    const int lane = t & 63;
    const int wvi  = t >> 6;
    int pc = __popc(out);
    int s = pc;
    #pragma unroll
    for (int off = 1; off < 64; off <<= 1) {
        int v = __shfl_up(s, off, 64);
        if (lane >= off) s += v;
    }
    if (lane == 63) wtot[wvi] = (uint32_t)s;
    __syncthreads();
    const uint32_t cnt = wtot[0] + wtot[1] + wtot[2];

    // ---- decoupled lookback (wave 0 only) ----
    if (wvi == 0) {
        if (lane == 0) atomicExch(&status[bid], AGG_F | cnt);
        uint32_t running = 0;
        if (bid > 0) {
            long jw = bid - 1;
            for (;;) {
                int j = (int)(jw - lane);
                uint32_t v = 0;
                const bool valid = (j >= 0);
                if (valid) {
                    for (;;) {
                        v = atomicOr(&status[j], 0u);
                        if (v & (AGG_F | INCL_F)) break;
                        __builtin_amdgcn_s_sleep(1);
                    }
                }
                unsigned long long im = __ballot(valid && (v & INCL_F));
                if (im) {
                    int fi = __ffsll((long long)im) - 1;  // closest INCL
                    uint32_t contrib = (lane <= fi && valid) ? (v & VMASK) : 0u;
                    #pragma unroll
                    for (int off = 32; off; off >>= 1)
                        contrib += __shfl_xor(contrib, off, 64);
                    running += contrib;
                    break;
                } else {
                    uint32_t contrib = valid ? (v & VMASK) : 0u;
                    #pragma unroll
                    for (int off = 32; off; off >>= 1)
                        contrib += __shfl_xor(contrib, off, 64);
                    running += contrib;
                    jw -= 64;
                    if (jw < 0) break;  // summed down through block 0
                }
            }
        }
        if (lane == 0) {
            atomicExch(&status[bid], INCL_F | ((running + cnt) & VMASK));
            exclSh = running;
        }
    }
    __syncthreads();

    // ---- emit ----
    const uint32_t excl = exclSh;
    int woff = (wvi == 0) ? 0 : ((wvi == 1) ? (int)wtot[0]
                                            : (int)(wtot[0] + wtot[1]));
    int base = (int)excl + woff + (s - pc);
    uint32_t x = out;
    while (x) {
        int b = __ffs(x) - 1;
        x &= x - 1;
        if (base < maxdet) {
            times[base] = r;
            chans[base] = wi * 32 + b;
        }
        base++;
    }
}

extern "C" void kernel_launch(void* const* d_in, const int* in_sizes, int n_in,
                              void* d_out, int out_size, void* d_ws, size_t ws_size,
                              hipStream_t stream) {
    const float* traces = (const float*)d_in[0];
    const float* locs   = (const float*)d_in[1];
    const int M = M_CH;
    const int N = in_sizes[0] / M;            // 150000
    const long nsamp = (long)N * M;           // 57,600,000
    const int maxdet = out_size / 2;          // 100000
    int* times = (int*)d_out;
    int* chans = times + maxdet;

    const long n4     = nsamp / 4;                          // 14,400,000
    const long nwords = nsamp / 32;                         // 1,800,000
    const int  nchunk = (N + CHUNK_ROWS - 1) / CHUNK_ROWS;  // 9375
    const int  nStat  = nchunk + 1;

    char* ws = (char*)d_ws;
    uint32_t* nEntries    = (uint32_t*)(ws + 0);            // 1536
    uint8_t*  entryWord   = (uint8_t*)(ws + 1536);          // 4608   -> 6144
    uint32_t* entryMask   = (uint32_t*)(ws + 6144);         // 18432  -> 24576
    uint32_t* status      = (uint32_t*)(ws + 24576);        // 37504  -> 62080
    uint32_t* candWords   = (uint32_t*)(ws + 65536);        // 7.2 MB

    // 1024 samples (32 words) per wave; 4 waves per block; +1 block does
    // neighbor masks; +fill blocks pre-fill -1 and zero the status array.
    const long nwaves = (nwords + 31) / 32;                 // 56250
    const int  cblocks = (int)((nwaves + 3) / 4);           // 14063
    const int  fillBlocks = (maxdet + 255) / 256;           // 391
    cand_kernel<<<cblocks + 1 + fillBlocks, 256, 0, stream>>>(
        traces, locs, n4, nwords, cblocks,
        candWords, nEntries, entryWord, entryMask,
        status, nStat, maxdet, times, chans);

    fused_kernel<<<nchunk, BM_WORDS, 0, stream>>>(
        traces, N, nwords, nEntries, entryWord, entryMask, candWords,
        status, maxdet, times, chans);
}

// Round 3
// 437.542 us; speedup vs baseline: 1.2932x; 1.2932x over previous
//
#include <hip/hip_runtime.h>
#include <stdint.h>

#define M_CH       384
#define TR         15
#define MARGIN     20
#define CHUNK_ROWS 16
#define BM_WORDS   192        // words per chunk = 16*384/32
#define WPR        12         // words per row = 384/32
#define WIN_ROWS   46         // CHUNK_ROWS + 2*TR

// spread 8 bits of x to positions 0,4,8,...,28
__device__ __forceinline__ uint32_t spread4(uint32_t x) {
    x = (x | (x << 12)) & 0x000F000Fu;
    x = (x | (x << 6))  & 0x03030303u;
    x = (x | (x << 3))  & 0x11111111u;
    return x;
}

// ---------------- K1: streaming threshold pass ----------------
// Roles by blockIdx: [0, nbrBlock) threshold; == nbrBlock neighbor masks;
// > nbrBlock: pre-fill output with -1 (emit overwrites [0,total)).
// Wave handles 256 contiguous float4s (1024 samples = 32 words).
__global__ __launch_bounds__(256)
void cand_kernel(const float* __restrict__ traces,
                 const float* __restrict__ locs,
                 long n4, long nwords, int nbrBlock,
                 uint32_t* __restrict__ candWords,
                 uint32_t* __restrict__ nEntries,
                 uint8_t* __restrict__ entryWord,
                 uint32_t* __restrict__ entryMask,
                 int maxdet, int* __restrict__ times, int* __restrict__ chans) {
    if ((int)blockIdx.x > nbrBlock) {
        // ---- fill role: poison-proof init ----
        int i = ((int)blockIdx.x - nbrBlock - 1) * 256 + threadIdx.x;
        if (i < maxdet) { times[i] = -1; chans[i] = -1; }
        return;
    }
    if ((int)blockIdx.x == nbrBlock) {
        // ---- neighbor-mask role (one block) ----
        __shared__ float lx[M_CH], ly[M_CH];
        const int t = threadIdx.x;
        for (int c = t; c < M_CH; c += 256) {
            lx[c] = locs[2 * c];
            ly[c] = locs[2 * c + 1];
        }
        __syncthreads();
        for (int c0 = t; c0 < M_CH; c0 += 256) {
            float x = lx[c0], y = ly[c0];
            int ne = 0;
            for (int k = 0; k < WPR; ++k) {
                uint32_t mk = 0;
                #pragma unroll
                for (int b = 0; b < 32; ++b) {
                    int c = k * 32 + b;
                    float dx = x - lx[c], dy = y - ly[c];
                    if (sqrtf(dx * dx + dy * dy) <= 100.0f) mk |= 1u << b;
                }
                if (mk) {
                    entryWord[c0 * WPR + ne] = (uint8_t)k;
                    entryMask[c0 * WPR + ne] = mk;
                    ne++;
                }
            }
            nEntries[c0] = (uint32_t)ne;
        }
        return;
    }

    const int lane = threadIdx.x & 63;
    const long wv = (((long)blockIdx.x * 256) + threadIdx.x) >> 6;
    const long fb = wv * 256;                  // first float4 of this wave
    uint64_t B00,B01,B02,B03, B10,B11,B12,B13,
             B20,B21,B22,B23, B30,B31,B32,B33;
    {
        float4 v0 = make_float4(0,0,0,0), v1 = v0, v2 = v0, v3 = v0;
        long i0 = fb + 0 * 64 + lane;
        long i1 = fb + 1 * 64 + lane;
        long i2 = fb + 2 * 64 + lane;
        long i3 = fb + 3 * 64 + lane;
        if (i0 < n4) v0 = ((const float4*)traces)[i0];
        if (i1 < n4) v1 = ((const float4*)traces)[i1];
        if (i2 < n4) v2 = ((const float4*)traces)[i2];
        if (i3 < n4) v3 = ((const float4*)traces)[i3];
        B00 = __ballot(v0.x <= -3.0f); B01 = __ballot(v0.y <= -3.0f);
        B02 = __ballot(v0.z <= -3.0f); B03 = __ballot(v0.w <= -3.0f);
        B10 = __ballot(v1.x <= -3.0f); B11 = __ballot(v1.y <= -3.0f);
        B12 = __ballot(v1.z <= -3.0f); B13 = __ballot(v1.w <= -3.0f);
        B20 = __ballot(v2.x <= -3.0f); B21 = __ballot(v2.y <= -3.0f);
        B22 = __ballot(v2.z <= -3.0f); B23 = __ballot(v2.w <= -3.0f);
        B30 = __ballot(v3.x <= -3.0f); B31 = __ballot(v3.y <= -3.0f);
        B32 = __ballot(v3.z <= -3.0f); B33 = __ballot(v3.w <= -3.0f);
    }
    if (lane < 32) {
        int k  = lane >> 3;           // which load group
        int sh = (lane & 7) * 8;      // which byte of the ballot
        uint64_t b0 = (k & 2) ? ((k & 1) ? B30 : B20) : ((k & 1) ? B10 : B00);
        uint64_t b1 = (k & 2) ? ((k & 1) ? B31 : B21) : ((k & 1) ? B11 : B01);
        uint64_t b2 = (k & 2) ? ((k & 1) ? B32 : B22) : ((k & 1) ? B12 : B02);
        uint64_t b3 = (k & 2) ? ((k & 1) ? B33 : B23) : ((k & 1) ? B13 : B03);
        uint32_t w = spread4((uint32_t)(b0 >> sh) & 0xFFu)
                   | (spread4((uint32_t)(b1 >> sh) & 0xFFu) << 1)
                   | (spread4((uint32_t)(b2 >> sh) & 0xFFu) << 2)
                   | (spread4((uint32_t)(b3 >> sh) & 0xFFu) << 3);
        long wIdx = wv * 32 + lane;
        if (wIdx < nwords) candWords[wIdx] = w;
    }
}

// ---------------- K2: validate via LDS-staged window + per-chunk count ----
// Block = 192 threads = one 16-row chunk; window (46 rows x 12 words) is
// contiguous in candWords -> coalesced stage into LDS. Fast path: per
// candidate/entry a 31-word OR from LDS; zero global loads when clean.
// Slow path (rare): value comparison on actual hits only.
__global__ __launch_bounds__(192)
void validate_count_kernel(const float* __restrict__ traces, int N, long nwords,
                           const uint32_t* __restrict__ nEntries,
                           const uint8_t* __restrict__ entryWord,
                           const uint32_t* __restrict__ entryMask,
                           const uint32_t* __restrict__ candWords,
                           uint32_t* __restrict__ validOut,
                           uint32_t* __restrict__ chunkCounts) {
    __shared__ uint32_t win[WIN_ROWS * WPR];   // 552 words = 2.2 KB
    __shared__ uint32_t red[3];
    const int t = threadIdx.x;
    const int r0 = (int)blockIdx.x * CHUNK_ROWS;

    {
        const long gbase = (long)(r0 - TR) * WPR;
        #pragma unroll
        for (int i0 = 0; i0 < WIN_ROWS * WPR; i0 += 192) {
            int i = i0 + t;
            if (i < WIN_ROWS * WPR) {
                long g = gbase + i;
                win[i] = (g >= 0 && g < nwords) ? candWords[g] : 0u;
            }
        }
    }
    __syncthreads();

    const int lr = t / WPR;        // local row 0..15
    const int wi = t - lr * WPR;   // word-in-row 0..11
    const int r  = r0 + lr;
    const long w = (long)blockIdx.x * BM_WORDS + t;

    uint32_t out = 0;
    if (w < nwords) {
        uint32_t word = win[(lr + TR) * WPR + wi];
        if (word && r >= MARGIN && r < N - MARGIN) {
            out = word;
            uint32_t tmp = word;
            while (tmp) {
                int bit = __ffs(tmp) - 1;
                tmp &= tmp - 1;
                const int c = wi * 32 + bit;
                const uint32_t selfbit = 1u << bit;
                const int ne = (int)nEntries[c];

                // ---- fast pass: any competitor bit anywhere in window? ----
                uint32_t anyComp = 0;
                for (int k = 0; k < ne; ++k) {
                    int wiE = (int)entryWord[c * WPR + k];
                    uint32_t em = entryMask[c * WPR + k];
                    const uint32_t* colp = &win[lr * WPR + wiE];
                    uint32_t orw = 0;
                    #pragma unroll
                    for (int dt = 0; dt < 31; ++dt) {
                        uint32_t h = colp[dt * WPR];
                        if (dt == TR) h &= (wiE == wi) ? ~selfbit : 0xFFFFFFFFu;
                        orw |= h & em;
                    }
                    anyComp |= orw;
                }

                if (anyComp) {
                    // ---- slow path: value comparison on actual hits ----
                    float raw = traces[(long)r * M_CH + c];
                    bool bad = false;
                    for (int k = 0; k < ne && !bad; ++k) {
                        int wiE = (int)entryWord[c * WPR + k];
                        uint32_t em = entryMask[c * WPR + k];
                        const uint32_t* colp = &win[lr * WPR + wiE];
                        #pragma unroll
                        for (int dt = 0; dt < 31; ++dt) {
                            uint32_t h = colp[dt * WPR] & em;
                            if (dt == TR && wiE == wi) h &= ~selfbit;
                            while (h) {
                                int b2 = __ffs(h) - 1;
                                h &= h - 1;
                                float v = traces[(long)(r - TR + dt) * M_CH + wiE * 32 + b2];
                                if (v < raw) bad = true;
                            }
                        }
                    }
                    if (bad) out &= ~selfbit;
                }
            }
        }
        validOut[w] = out;
    }
    int pc = __popc(out);
    #pragma unroll
    for (int off = 32; off; off >>= 1) pc += __shfl_xor(pc, off, 64);
    if ((t & 63) == 0) red[t >> 6] = (uint32_t)pc;
    __syncthreads();
    if (t == 0) chunkCounts[blockIdx.x] = red[0] + red[1] + red[2];
}

// ---------------- K3: emit with REDUNDANT prefix (no scan kernel) --------
// Block handles 4 consecutive chunks (one per wave). Its base prefix is
// computed locally: 256 threads cooperatively sum counts[0..c0) — 37.5 KB
// of L1/L2-resident data, ~1-2 us aggregate across the grid, zero atomics,
// zero inter-block dependencies. Intra-block: per-wave ordered bit emit.
__global__ __launch_bounds__(256)
void emit_kernel(const uint32_t* __restrict__ validOut,
                 const uint32_t* __restrict__ chunkCounts,
                 int nchunk, int maxdet,
                 int* __restrict__ times, int* __restrict__ chans) {
    __shared__ uint32_t sred[4];
    __shared__ uint32_t cnts4[4];
    const int t = threadIdx.x;
    const int lane = t & 63;
    const int wv   = t >> 6;
    const int c0 = (int)blockIdx.x * 4;

    if (t < 4) cnts4[t] = (c0 + t < nchunk) ? chunkCounts[c0 + t] : 0u;

    // cooperative exclusive prefix: sum counts[0..c0)
    uint32_t part = 0;
    for (int i = t; i < c0; i += 256) part += chunkCounts[i];
    #pragma unroll
    for (int off = 32; off; off >>= 1) part += __shfl_xor(part, off, 64);
    if (lane == 0) sred[wv] = part;
    __syncthreads();
    uint32_t base0 = sred[0] + sred[1] + sred[2] + sred[3];

    const int chunkId = c0 + wv;
    if (chunkId >= nchunk) return;
    uint32_t basePref = base0;
    #pragma unroll
    for (int k = 0; k < 3; ++k) if (k < wv) basePref += cnts4[k];

    const uint32_t* wp = validOut + (long)chunkId * BM_WORDS + lane * 3;
    uint32_t b0 = wp[0], b1 = wp[1], b2 = wp[2];
    int local = __popc(b0) + __popc(b1) + __popc(b2);

    int s = local;
    #pragma unroll
    for (int off = 1; off < 64; off <<= 1) {
        int v = __shfl_up(s, off, 64);
        if (lane >= off) s += v;
    }
    int base = (int)basePref + (s - local);
    int r0 = chunkId * CHUNK_ROWS;

    uint32_t words[3] = { b0, b1, b2 };
    #pragma unroll
    for (int q = 0; q < 3; ++q) {
        uint32_t x = words[q];
        int fbase = (lane * 3 + q) * 32;
        while (x) {
            int b = __ffs(x) - 1;
            x &= x - 1;
            int f = fbase + b;
            int n = f / M_CH;
            int ch = f - n * M_CH;
            if (base < maxdet) {
                times[base] = r0 + n;
                chans[base] = ch;
            }
            base++;
        }
    }
}

extern "C" void kernel_launch(void* const* d_in, const int* in_sizes, int n_in,
                              void* d_out, int out_size, void* d_ws, size_t ws_size,
                              hipStream_t stream) {
    const float* traces = (const float*)d_in[0];
    const float* locs   = (const float*)d_in[1];
    const int M = M_CH;
    const int N = in_sizes[0] / M;            // 150000
    const long nsamp = (long)N * M;           // 57,600,000
    const int maxdet = out_size / 2;          // 100000
    int* times = (int*)d_out;
    int* chans = times + maxdet;

    const long n4     = nsamp / 4;                          // 14,400,000
    const long nwords = nsamp / 32;                         // 1,800,000
    const int  nchunk = (N + CHUNK_ROWS - 1) / CHUNK_ROWS;  // 9375

    char* ws = (char*)d_ws;
    uint32_t* nEntries    = (uint32_t*)(ws + 0);            // 1536
    uint8_t*  entryWord   = (uint8_t*)(ws + 1536);          // 4608   -> 6144
    uint32_t* entryMask   = (uint32_t*)(ws + 6144);         // 18432  -> 24576
    uint32_t* chunkCounts = (uint32_t*)(ws + 24576);        // 37500  -> 65536 (pad)
    uint32_t* candWords   = (uint32_t*)(ws + 65536);        // 7.2 MB -> 7265536
    uint32_t* validOut    = (uint32_t*)(ws + 7265536);      // 7.2 MB -> 14.5 MB

    // 1024 samples (32 words) per wave; 4 waves per block; +1 block does
    // neighbor masks; + fill blocks pre-fill the output with -1.
    const long nwaves = (nwords + 31) / 32;                 // 56250
    const int  cblocks = (int)((nwaves + 3) / 4);           // 14063
    const int  fillBlocks = (maxdet + 255) / 256;           // 391
    cand_kernel<<<cblocks + 1 + fillBlocks, 256, 0, stream>>>(
        traces, locs, n4, nwords, cblocks,
        candWords, nEntries, entryWord, entryMask,
        maxdet, times, chans);

    validate_count_kernel<<<nchunk, BM_WORDS, 0, stream>>>(
        traces, N, nwords, nEntries, entryWord, entryMask, candWords,
        validOut, chunkCounts);

    const int emitBlocks = (nchunk + 3) / 4;                // 2344
    emit_kernel<<<emitBlocks, 256, 0, stream>>>(
        validOut, chunkCounts, nchunk, maxdet, times, chans);
}

// Round 4
// 422.970 us; speedup vs baseline: 1.3378x; 1.0345x over previous
//
#include <hip/hip_runtime.h>
#include <stdint.h>

#define M_CH       384
#define TR         15
#define MARGIN     20
#define CHUNK_ROWS 16
#define BM_WORDS   192        // words per chunk = 16*384/32
#define WPR        12         // words per row = 384/32
#define WIN_ROWS   46         // CHUNK_ROWS + 2*TR

// spread 8 bits of x to positions 0,4,8,...,28
__device__ __forceinline__ uint32_t spread4(uint32_t x) {
    x = (x | (x << 12)) & 0x000F000Fu;
    x = (x | (x << 6))  & 0x03030303u;
    x = (x | (x << 3))  & 0x11111111u;
    return x;
}

// ---------------- K1: streaming threshold pass (grid-stride) ----------------
// Roles by blockIdx: [0, workBlocks) threshold; == workBlocks neighbor masks;
// > workBlocks: pre-fill output with -1 (emit overwrites [0,total)).
// Each wave-iteration covers a 2048-sample tile (512 float4 = 64 words):
// 8 coalesced 1-KB loads in flight, 32 ballots, then ALL 64 lanes build one
// word each (lane = word index; k = lane>>3 selects ballot group, byte
// lane&7 slices it) and store 256 B contiguous. 28125 tiles exactly.
__global__ __launch_bounds__(256)
void cand_kernel(const float* __restrict__ traces,
                 const float* __restrict__ locs,
                 long n4, long nwords, int workBlocks,
                 uint32_t* __restrict__ candWords,
                 uint32_t* __restrict__ nEntries,
                 uint8_t* __restrict__ entryWord,
                 uint32_t* __restrict__ entryMask,
                 int maxdet, int* __restrict__ times, int* __restrict__ chans) {
    if ((int)blockIdx.x > workBlocks) {
        // ---- fill role: poison-proof init ----
        int i = ((int)blockIdx.x - workBlocks - 1) * 256 + threadIdx.x;
        if (i < maxdet) { times[i] = -1; chans[i] = -1; }
        return;
    }
    if ((int)blockIdx.x == workBlocks) {
        // ---- neighbor-mask role (one block) ----
        __shared__ float lx[M_CH], ly[M_CH];
        const int t = threadIdx.x;
        for (int c = t; c < M_CH; c += 256) {
            lx[c] = locs[2 * c];
            ly[c] = locs[2 * c + 1];
        }
        __syncthreads();
        for (int c0 = t; c0 < M_CH; c0 += 256) {
            float x = lx[c0], y = ly[c0];
            int ne = 0;
            for (int k = 0; k < WPR; ++k) {
                uint32_t mk = 0;
                #pragma unroll
                for (int b = 0; b < 32; ++b) {
                    int c = k * 32 + b;
                    float dx = x - lx[c], dy = y - ly[c];
                    if (sqrtf(dx * dx + dy * dy) <= 100.0f) mk |= 1u << b;
                }
                if (mk) {
                    entryWord[c0 * WPR + ne] = (uint8_t)k;
                    entryMask[c0 * WPR + ne] = mk;
                    ne++;
                }
            }
            nEntries[c0] = (uint32_t)ne;
        }
        return;
    }

    const int lane = threadIdx.x & 63;
    const long nTiles = (nwords + 63) >> 6;                 // 28125 (exact)
    const long wv0 = (((long)blockIdx.x * 256) + threadIdx.x) >> 6;
    const long nwv = (long)workBlocks * 4;

    for (long tile = wv0; tile < nTiles; tile += nwv) {
        const long f0 = tile << 9;             // first float4 of tile (512/tile)
        float4 v0 = make_float4(0,0,0,0), v1 = v0, v2 = v0, v3 = v0,
               v4 = v0, v5 = v0, v6 = v0, v7 = v0;
        {
            long i0 = f0 + 0 * 64 + lane; if (i0 < n4) v0 = ((const float4*)traces)[i0];
            long i1 = f0 + 1 * 64 + lane; if (i1 < n4) v1 = ((const float4*)traces)[i1];
            long i2 = f0 + 2 * 64 + lane; if (i2 < n4) v2 = ((const float4*)traces)[i2];
            long i3 = f0 + 3 * 64 + lane; if (i3 < n4) v3 = ((const float4*)traces)[i3];
            long i4 = f0 + 4 * 64 + lane; if (i4 < n4) v4 = ((const float4*)traces)[i4];
            long i5 = f0 + 5 * 64 + lane; if (i5 < n4) v5 = ((const float4*)traces)[i5];
            long i6 = f0 + 6 * 64 + lane; if (i6 < n4) v6 = ((const float4*)traces)[i6];
            long i7 = f0 + 7 * 64 + lane; if (i7 < n4) v7 = ((const float4*)traces)[i7];
        }
        uint64_t B00 = __ballot(v0.x <= -3.0f), B01 = __ballot(v0.y <= -3.0f),
                 B02 = __ballot(v0.z <= -3.0f), B03 = __ballot(v0.w <= -3.0f);
        uint64_t B10 = __ballot(v1.x <= -3.0f), B11 = __ballot(v1.y <= -3.0f),
                 B12 = __ballot(v1.z <= -3.0f), B13 = __ballot(v1.w <= -3.0f);
        uint64_t B20 = __ballot(v2.x <= -3.0f), B21 = __ballot(v2.y <= -3.0f),
                 B22 = __ballot(v2.z <= -3.0f), B23 = __ballot(v2.w <= -3.0f);
        uint64_t B30 = __ballot(v3.x <= -3.0f), B31 = __ballot(v3.y <= -3.0f),
                 B32 = __ballot(v3.z <= -3.0f), B33 = __ballot(v3.w <= -3.0f);
        uint64_t B40 = __ballot(v4.x <= -3.0f), B41 = __ballot(v4.y <= -3.0f),
                 B42 = __ballot(v4.z <= -3.0f), B43 = __ballot(v4.w <= -3.0f);
        uint64_t B50 = __ballot(v5.x <= -3.0f), B51 = __ballot(v5.y <= -3.0f),
                 B52 = __ballot(v5.z <= -3.0f), B53 = __ballot(v5.w <= -3.0f);
        uint64_t B60 = __ballot(v6.x <= -3.0f), B61 = __ballot(v6.y <= -3.0f),
                 B62 = __ballot(v6.z <= -3.0f), B63 = __ballot(v6.w <= -3.0f);
        uint64_t B70 = __ballot(v7.x <= -3.0f), B71 = __ballot(v7.y <= -3.0f),
                 B72 = __ballot(v7.z <= -3.0f), B73 = __ballot(v7.w <= -3.0f);

        const int k  = lane >> 3;          // ballot group 0..7
        const int sh = (lane & 7) * 8;     // byte within the ballot
        uint64_t b0 = (k & 4) ? ((k & 2) ? ((k & 1) ? B70 : B60) : ((k & 1) ? B50 : B40))
                              : ((k & 2) ? ((k & 1) ? B30 : B20) : ((k & 1) ? B10 : B00));
        uint64_t b1 = (k & 4) ? ((k & 2) ? ((k & 1) ? B71 : B61) : ((k & 1) ? B51 : B41))
                              : ((k & 2) ? ((k & 1) ? B31 : B21) : ((k & 1) ? B11 : B01));
        uint64_t b2 = (k & 4) ? ((k & 2) ? ((k & 1) ? B72 : B62) : ((k & 1) ? B52 : B42))
                              : ((k & 2) ? ((k & 1) ? B32 : B22) : ((k & 1) ? B12 : B02));
        uint64_t b3 = (k & 4) ? ((k & 2) ? ((k & 1) ? B73 : B63) : ((k & 1) ? B53 : B43))
                              : ((k & 2) ? ((k & 1) ? B33 : B23) : ((k & 1) ? B13 : B03));
        uint32_t w = spread4((uint32_t)(b0 >> sh) & 0xFFu)
                   | (spread4((uint32_t)(b1 >> sh) & 0xFFu) << 1)
                   | (spread4((uint32_t)(b2 >> sh) & 0xFFu) << 2)
                   | (spread4((uint32_t)(b3 >> sh) & 0xFFu) << 3);
        long wIdx = (tile << 6) + lane;
        if (wIdx < nwords) candWords[wIdx] = w;
    }
}

// ---------------- K2: validate via LDS-staged window + per-chunk count ----
// Block = 192 threads = one 16-row chunk; window (46 rows x 12 words) is
// contiguous in candWords -> coalesced stage into LDS. Fast path: per
// candidate/entry a 31-word OR from LDS; zero global loads when clean.
// Slow path (rare): value comparison on actual hits only.
__global__ __launch_bounds__(192)
void validate_count_kernel(const float* __restrict__ traces, int N, long nwords,
                           const uint32_t* __restrict__ nEntries,
                           const uint8_t* __restrict__ entryWord,
                           const uint32_t* __restrict__ entryMask,
                           const uint32_t* __restrict__ candWords,
                           uint32_t* __restrict__ validOut,
                           uint32_t* __restrict__ chunkCounts) {
    __shared__ uint32_t win[WIN_ROWS * WPR];   // 552 words = 2.2 KB
    __shared__ uint32_t red[3];
    const int t = threadIdx.x;
    const int r0 = (int)blockIdx.x * CHUNK_ROWS;

    {
        const long gbase = (long)(r0 - TR) * WPR;
        #pragma unroll
        for (int i0 = 0; i0 < WIN_ROWS * WPR; i0 += 192) {
            int i = i0 + t;
            if (i < WIN_ROWS * WPR) {
                long g = gbase + i;
                win[i] = (g >= 0 && g < nwords) ? candWords[g] : 0u;
            }
        }
    }
    __syncthreads();

    const int lr = t / WPR;        // local row 0..15
    const int wi = t - lr * WPR;   // word-in-row 0..11
    const int r  = r0 + lr;
    const long w = (long)blockIdx.x * BM_WORDS + t;

    uint32_t out = 0;
    if (w < nwords) {
        uint32_t word = win[(lr + TR) * WPR + wi];
        if (word && r >= MARGIN && r < N - MARGIN) {
            out = word;
            uint32_t tmp = word;
            while (tmp) {
                int bit = __ffs(tmp) - 1;
                tmp &= tmp - 1;
                const int c = wi * 32 + bit;
                const uint32_t selfbit = 1u << bit;
                const int ne = (int)nEntries[c];

                // ---- fast pass: any competitor bit anywhere in window? ----
                uint32_t anyComp = 0;
                for (int k = 0; k < ne; ++k) {
                    int wiE = (int)entryWord[c * WPR + k];
                    uint32_t em = entryMask[c * WPR + k];
                    const uint32_t* colp = &win[lr * WPR + wiE];
                    uint32_t orw = 0;
                    #pragma unroll
                    for (int dt = 0; dt < 31; ++dt) {
                        uint32_t h = colp[dt * WPR];
                        if (dt == TR) h &= (wiE == wi) ? ~selfbit : 0xFFFFFFFFu;
                        orw |= h & em;
                    }
                    anyComp |= orw;
                }

                if (anyComp) {
                    // ---- slow path: value comparison on actual hits ----
                    float raw = traces[(long)r * M_CH + c];
                    bool bad = false;
                    for (int k = 0; k < ne && !bad; ++k) {
                        int wiE = (int)entryWord[c * WPR + k];
                        uint32_t em = entryMask[c * WPR + k];
                        const uint32_t* colp = &win[lr * WPR + wiE];
                        #pragma unroll
                        for (int dt = 0; dt < 31; ++dt) {
                            uint32_t h = colp[dt * WPR] & em;
                            if (dt == TR && wiE == wi) h &= ~selfbit;
                            while (h) {
                                int b2 = __ffs(h) - 1;
                                h &= h - 1;
                                float v = traces[(long)(r - TR + dt) * M_CH + wiE * 32 + b2];
                                if (v < raw) bad = true;
                            }
                        }
                    }
                    if (bad) out &= ~selfbit;
                }
            }
        }
        validOut[w] = out;
    }
    int pc = __popc(out);
    #pragma unroll
    for (int off = 32; off; off >>= 1) pc += __shfl_xor(pc, off, 64);
    if ((t & 63) == 0) red[t >> 6] = (uint32_t)pc;
    __syncthreads();
    if (t == 0) chunkCounts[blockIdx.x] = red[0] + red[1] + red[2];
}

// ---------------- K3: emit with REDUNDANT prefix (no scan kernel) --------
// Block handles 4 consecutive chunks (one per wave). Its base prefix is
// computed locally: 256 threads cooperatively sum counts[0..c0) — 37.5 KB
// of L1/L2-resident data, zero atomics, zero inter-block dependencies.
__global__ __launch_bounds__(256)
void emit_kernel(const uint32_t* __restrict__ validOut,
                 const uint32_t* __restrict__ chunkCounts,
                 int nchunk, int maxdet,
                 int* __restrict__ times, int* __restrict__ chans) {
    __shared__ uint32_t sred[4];
    __shared__ uint32_t cnts4[4];
    const int t = threadIdx.x;
    const int lane = t & 63;
    const int wv   = t >> 6;
    const int c0 = (int)blockIdx.x * 4;

    if (t < 4) cnts4[t] = (c0 + t < nchunk) ? chunkCounts[c0 + t] : 0u;

    // cooperative exclusive prefix: sum counts[0..c0)
    uint32_t part = 0;
    for (int i = t; i < c0; i += 256) part += chunkCounts[i];
    #pragma unroll
    for (int off = 32; off; off >>= 1) part += __shfl_xor(part, off, 64);
    if (lane == 0) sred[wv] = part;
    __syncthreads();
    uint32_t base0 = sred[0] + sred[1] + sred[2] + sred[3];

    const int chunkId = c0 + wv;
    if (chunkId >= nchunk) return;
    uint32_t basePref = base0;
    #pragma unroll
    for (int k = 0; k < 3; ++k) if (k < wv) basePref += cnts4[k];

    const uint32_t* wp = validOut + (long)chunkId * BM_WORDS + lane * 3;
    uint32_t b0 = wp[0], b1 = wp[1], b2 = wp[2];
    int local = __popc(b0) + __popc(b1) + __popc(b2);

    int s = local;
    #pragma unroll
    for (int off = 1; off < 64; off <<= 1) {
        int v = __shfl_up(s, off, 64);
        if (lane >= off) s += v;
    }
    int base = (int)basePref + (s - local);
    int r0 = chunkId * CHUNK_ROWS;

    uint32_t words[3] = { b0, b1, b2 };
    #pragma unroll
    for (int q = 0; q < 3; ++q) {
        uint32_t x = words[q];
        int fbase = (lane * 3 + q) * 32;
        while (x) {
            int b = __ffs(x) - 1;
            x &= x - 1;
            int f = fbase + b;
            int n = f / M_CH;
            int ch = f - n * M_CH;
            if (base < maxdet) {
                times[base] = r0 + n;
                chans[base] = ch;
            }
            base++;
        }
    }
}

extern "C" void kernel_launch(void* const* d_in, const int* in_sizes, int n_in,
                              void* d_out, int out_size, void* d_ws, size_t ws_size,
                              hipStream_t stream) {
    const float* traces = (const float*)d_in[0];
    const float* locs   = (const float*)d_in[1];
    const int M = M_CH;
    const int N = in_sizes[0] / M;            // 150000
    const long nsamp = (long)N * M;           // 57,600,000
    const int maxdet = out_size / 2;          // 100000
    int* times = (int*)d_out;
    int* chans = times + maxdet;

    const long n4     = nsamp / 4;                          // 14,400,000
    const long nwords = nsamp / 32;                         // 1,800,000
    const int  nchunk = (N + CHUNK_ROWS - 1) / CHUNK_ROWS;  // 9375

    char* ws = (char*)d_ws;
    uint32_t* nEntries    = (uint32_t*)(ws + 0);            // 1536
    uint8_t*  entryWord   = (uint8_t*)(ws + 1536);          // 4608   -> 6144
    uint32_t* entryMask   = (uint32_t*)(ws + 6144);         // 18432  -> 24576
    uint32_t* chunkCounts = (uint32_t*)(ws + 24576);        // 37500  -> 65536 (pad)
    uint32_t* candWords   = (uint32_t*)(ws + 65536);        // 7.2 MB -> 7265536
    uint32_t* validOut    = (uint32_t*)(ws + 7265536);      // 7.2 MB -> 14.5 MB

    // persistent grid-stride threshold pass: 2048 work blocks = 8 blocks/CU,
    // each wave iterates ~3.4 tiles of 2048 samples; +1 nbr block; +fill.
    const int  workBlocks = 2048;
    const int  fillBlocks = (maxdet + 255) / 256;           // 391
    cand_kernel<<<workBlocks + 1 + fillBlocks, 256, 0, stream>>>(
        traces, locs, n4, nwords, workBlocks,
        candWords, nEntries, entryWord, entryMask,
        maxdet, times, chans);

    validate_count_kernel<<<nchunk, BM_WORDS, 0, stream>>>(
        traces, N, nwords, nEntries, entryWord, entryMask, candWords,
        validOut, chunkCounts);

    const int emitBlocks = (nchunk + 3) / 4;                // 2344
    emit_kernel<<<emitBlocks, 256, 0, stream>>>(
        validOut, chunkCounts, nchunk, maxdet, times, chans);
}